// Round 1
// baseline (187.300 us; speedup 1.0000x reference)
//
#include <hip/hip_runtime.h>
#include <math.h>
#include <stdint.h>

#define VOCAB 100000
#define NB    1024
#define QLEN  32
#define DLEN  256
#define EMBED 128
#define KNUM  11

typedef __attribute__((ext_vector_type(8))) short bf16x8;   // 8 bf16 = 4 VGPRs
typedef __attribute__((ext_vector_type(4))) float f32x4;

// Gaussian chain: mus -0.9..0.9 step 0.2 (sigma 0.1) + exact mu=1 sigma=.001
#define HALF_L2E 0.7213475204444817f   // 0.5*log2(e)
#define TWO_L2E  2.8853900817779268f   // 2*log2(e)
#define EM4      0.018315638888734179f // e^-4

// Legacy fallback tile constants
#define SSTR  68
#define SHALF (16 * SSTR)

// ---------- prepass: fp32 table -> bf16 table + bf16-consistent inv-norms ----
__global__ __launch_bounds__(256)
void cvt_table(const float* __restrict__ emb, ushort* __restrict__ ebf,
               float* __restrict__ inorm)
{
    const int row = blockIdx.x * 8 + (threadIdx.x >> 5);
    const int l32 = threadIdx.x & 31;
    const float4 v = *((const float4*)(emb + (size_t)row * EMBED) + l32);
    union { float f; unsigned u; } x0, x1, x2, x3;
    x0.f = v.x; x1.f = v.y; x2.f = v.z; x3.f = v.w;
    const unsigned r0 = x0.u + 0x8000u, r1 = x1.u + 0x8000u;  // round-half-up
    const unsigned r2 = x2.u + 0x8000u, r3 = x3.u + 0x8000u;
    uint2 packed;
    packed.x = (r0 >> 16) | (r1 & 0xFFFF0000u);
    packed.y = (r2 >> 16) | (r3 & 0xFFFF0000u);
    *((uint2*)(ebf + (size_t)row * EMBED) + l32) = packed;
    x0.u = r0 & 0xFFFF0000u; x1.u = r1 & 0xFFFF0000u;
    x2.u = r2 & 0xFFFF0000u; x3.u = r3 & 0xFFFF0000u;
    float n = x0.f * x0.f + x1.f * x1.f + x2.f * x2.f + x3.f * x3.f;
    #pragma unroll
    for (int m = 1; m < 32; m <<= 1) n += __shfl_xor(n, m);
    if (l32 == 0) inorm[row] = __builtin_amdgcn_rsqf(n);
}

// ---------------------------------------------------------------------------
// global_load_lds helper: 16B per lane, per-lane scattered GLOBAL address,
// wave-uniform LDS base (HW writes base + lane*16). AS casts via the CK
// uintptr detour (generic-LDS low 32 bits == LDS offset on gfx9).
__device__ __forceinline__ void gl_lds16(const ushort* g, ushort* lds)
{
    auto gp = reinterpret_cast<const __attribute__((address_space(1))) void*>(
        reinterpret_cast<uintptr_t>(g));
    auto lp = reinterpret_cast<__attribute__((address_space(3))) void*>(
        static_cast<unsigned>(reinterpret_cast<uintptr_t>(lds)));
    __builtin_amdgcn_global_load_lds(gp, lp, 16, 0, 0);
}

#define WAITV(n) asm volatile("s_waitcnt vmcnt(" #n ")" ::: "memory")

// ---------------------------------------------------------------------------
// New main kernel: 2 waves/block (wave w owns q rows w*16..w*16+15).
// Doc rows staged to LDS with global_load_lds in 16-row (4KB) chunks,
// layout [buf][kk][lane][16B] so DMA write AND ds_read_b128 are linear.
// 4-buffer rotation, 3 chunks in flight, counted vmcnt(4) (never 0 in loop),
// 1 raw s_barrier per chunk. Buffer-reuse safety: STAGE(c) at iter nt writes
// buf (nt+3)&3, last read at chunk nt-1, and all waves passed barrier(nt)
// strictly after finishing their chunk nt-1 reads.
__global__ __launch_bounds__(128, 4)
void knrm_pair2(const ushort* __restrict__ ebf,
                const float* __restrict__ inorm,
                const float* __restrict__ mlp_w,
                const int* __restrict__ q1, const int* __restrict__ d1,
                const int* __restrict__ q2, const int* __restrict__ d2,
                float* __restrict__ logits)
{
    const int b    = blockIdx.x;
    const int pair = blockIdx.y;
    const int t    = threadIdx.x;
    const int w    = t >> 6;        // wave id = q half
    const int l    = t & 63;
    const int l15  = l & 15;
    const int quad = l >> 4;

    const int* __restrict__ qry = (pair == 0 ? q1 : q2) + b * QLEN;
    const int* __restrict__ doc = (pair == 0 ? d1 : d2) + b * DLEN;

    __shared__ __align__(16) ushort s_doc[4][4][64][8];  // 16 KB: [buf][kk][lane][16B]
    __shared__ __align__(16) float  s_sim[2][16][20];    // 2.5 KB, stride 20 (80B, 16B-aligned)
    __shared__ float s_part[2];

    // ---- batch 1: id loads (oldest vmem) ----
    int dcid[16];                                  // doc[c*16 + l15], c=0..15
    #pragma unroll
    for (int c = 0; c < 16; ++c) dcid[c] = doc[c * 16 + l15];
    const int qid = qry[w * 16 + l15];
    int qrr[4];
    #pragma unroll
    for (int r = 0; r < 4; ++r) qrr[r] = qry[w * 16 + quad * 4 + r];

    // ---- batch 2: dependent gathers + all loop-invariant vmem, so that
    //      EVERYTHING non-stage is older than the first stage (vmcnt counting) ----
    float idnv[16];
    #pragma unroll
    for (int c = 0; c < 16; ++c) idnv[c] = inorm[dcid[c]];
    float riqw[4];
    #pragma unroll
    for (int r = 0; r < 4; ++r) riqw[r] = inorm[qrr[r]];
    bf16x8 aq[4];                                  // A-frags: row qry[w*16+l15]
    {
        const ushort* qp = ebf + (size_t)qid * EMBED + quad * 8;
        #pragma unroll
        for (int kk = 0; kk < 4; ++kk) aq[kk] = *(const bf16x8*)(qp + kk * 32);
    }
    float wk[KNUM];
    #pragma unroll
    for (int k = 0; k < KNUM; ++k) wk[k] = mlp_w[k];

    // ---- staging: wave w DMAs kk = 2w, 2w+1 of each chunk (2 instr/chunk/wave)
    #define STAGE(c)                                                              \
    {                                                                             \
        const ushort* gbase = ebf + (size_t)dcid[c] * EMBED + quad * 8;           \
        gl_lds16(gbase + (2 * w) * 32,     &s_doc[(c) & 3][2 * w][0][0]);         \
        gl_lds16(gbase + (2 * w + 1) * 32, &s_doc[(c) & 3][2 * w + 1][0][0]);     \
    }

    STAGE(0); STAGE(1); STAGE(2);

    float ksum[KNUM];
    #pragma unroll
    for (int k = 0; k < KNUM; ++k) ksum[k] = 0.f;

    #pragma unroll
    for (int nt = 0; nt < 16; ++nt) {
        // own chunk-nt stages retired (outstanding: 2 newest chunks = 4 instr)
        if      (nt <= 13) WAITV(4);
        else if (nt == 14) WAITV(2);
        else               WAITV(0);
        __builtin_amdgcn_s_barrier();            // both waves' chunk nt in LDS
        __builtin_amdgcn_sched_barrier(0);       // no ds_read hoists above barrier

        if (nt + 3 < 16) {
            switch (nt + 3) {                     // keep dcid[] statically indexed
                case 3:  STAGE(3);  break;
                case 4:  STAGE(4);  break;
                case 5:  STAGE(5);  break;
                case 6:  STAGE(6);  break;
                case 7:  STAGE(7);  break;
                case 8:  STAGE(8);  break;
                case 9:  STAGE(9);  break;
                case 10: STAGE(10); break;
                case 11: STAGE(11); break;
                case 12: STAGE(12); break;
                case 13: STAGE(13); break;
                case 14: STAGE(14); break;
                case 15: STAGE(15); break;
            }
        }

        // ---- MFMA: 16 q-rows x 16 doc-cols x K=128 ----
        f32x4 acc = {0.f, 0.f, 0.f, 0.f};
        #pragma unroll
        for (int kk = 0; kk < 4; ++kk) {
            const bf16x8 bb = *(const bf16x8*)&s_doc[nt & 3][kk][l][0];
            acc = __builtin_amdgcn_mfma_f32_16x16x32_bf16(aq[kk], bb, acc, 0, 0, 0);
        }

        // ---- pool this 16x16 tile (wave-private sim transpose in LDS) ----
        const float idn_c = idnv[nt];             // col = l15 of this chunk
        #pragma unroll
        for (int r = 0; r < 4; ++r)
            s_sim[w][quad * 4 + r][l15] = acc[r] * riqw[r] * idn_c;
        const f32x4 sv = *(const f32x4*)&s_sim[w][l15][quad * 4];
        #pragma unroll
        for (int e = 0; e < 4; ++e) {
            const float s  = sv[e];
            const float z  = fmaf(s, 10.f, -1.f);
            const float e0 = exp2f(-HALF_L2E * (z * z));
            float ru = exp2f(fmaf(z,  TWO_L2E, -TWO_L2E));
            float rd = exp2f(fmaf(z, -TWO_L2E, -TWO_L2E));
            ksum[5] += e0;
            float tt = e0;
            tt *= ru; ksum[6] += tt; ru *= EM4;
            tt *= ru; ksum[7] += tt; ru *= EM4;
            tt *= ru; ksum[8] += tt; ru *= EM4;
            tt *= ru; ksum[9] += tt;
            tt = e0;
            tt *= rd; ksum[4] += tt; rd *= EM4;
            tt *= rd; ksum[3] += tt; rd *= EM4;
            tt *= rd; ksum[2] += tt; rd *= EM4;
            tt *= rd; ksum[1] += tt; rd *= EM4;
            tt *= rd; ksum[0] += tt;
            // exact kernel (sigma=.001): ==1 iff token match (bf16 self-sim
            // 1+-3e-6; non-match needs cos>0.995 ~ 11 sigma)
            ksum[10] += (s > 0.995f) ? 1.f : 0.f;
        }
    }
    #undef STAGE

    // ---- reduce: quads hold disjoint col-quarters of row l15 ----
    #pragma unroll
    for (int k = 0; k < KNUM; ++k) {
        ksum[k] += __shfl_xor(ksum[k], 16);
        ksum[k] += __shfl_xor(ksum[k], 32);
    }
    float c = 0.f;
    #pragma unroll
    for (int k = 0; k < KNUM; ++k) c += wk[k] * log1pf(ksum[k]);
    c += __shfl_xor(c, 1); c += __shfl_xor(c, 2);
    c += __shfl_xor(c, 4); c += __shfl_xor(c, 8);   // sum over 16 q rows
    if (l == 0) s_part[w] = c;
    __syncthreads();
    if (t == 0) logits[pair * NB + b] = s_part[0] + s_part[1]; // mlp bias cancels
}

// ---------------------------------------------------------------------------
// fallback helper: fp32 -> bf16 frag + norm of rounded values
__device__ __forceinline__ bf16x8 cvt8(const float* p, float& nacc)
{
    uint4 a = *((const uint4*)p);
    uint4 b = *((const uint4*)(p + 4));
    unsigned u[8] = {a.x, a.y, a.z, a.w, b.x, b.y, b.z, b.w};
    bf16x8 r;
    #pragma unroll
    for (int i = 0; i < 8; ++i) {
        const unsigned q = u[i] + 0x8000u;
        r[i] = (short)(q >> 16);
        union { unsigned uu; float ff; } g; g.uu = q & 0xFFFF0000u;
        nacc = fmaf(g.ff, g.ff, nacc);
    }
    return r;
}

__device__ __forceinline__ void pool_half(float* __restrict__ wtile,
                                          const f32x4* __restrict__ a,
                                          const float* __restrict__ riq,
                                          const float* __restrict__ idn,
                                          float (*__restrict__ stot)[12],
                                          int mtbase, int l15, int quad)
{
    #pragma unroll
    for (int nt = 0; nt < 4; ++nt)
        #pragma unroll
        for (int r = 0; r < 4; ++r)
            wtile[(quad * 4 + r) * SSTR + nt * 16 + l15] = a[nt][r] * riq[r] * idn[nt];

    const float* rp = wtile + l15 * SSTR + quad * 16;
    float ksum[KNUM];
    #pragma unroll
    for (int k = 0; k < KNUM; ++k) ksum[k] = 0.f;

    #pragma unroll
    for (int i = 0; i < 4; ++i) {
        const f32x4 sv = *((const f32x4*)(rp + 4 * i));
        #pragma unroll
        for (int e = 0; e < 4; ++e) {
            const float s  = sv[e];
            const float z  = fmaf(s, 10.f, -1.f);
            const float e0 = exp2f(-HALF_L2E * (z * z));
            float ru = exp2f(fmaf(z,  TWO_L2E, -TWO_L2E));
            float rd = exp2f(fmaf(z, -TWO_L2E, -TWO_L2E));
            ksum[5] += e0;
            float tt = e0;
            tt *= ru; ksum[6] += tt; ru *= EM4;
            tt *= ru; ksum[7] += tt; ru *= EM4;
            tt *= ru; ksum[8] += tt; ru *= EM4;
            tt *= ru; ksum[9] += tt;
            tt = e0;
            tt *= rd; ksum[4] += tt; rd *= EM4;
            tt *= rd; ksum[3] += tt; rd *= EM4;
            tt *= rd; ksum[2] += tt; rd *= EM4;
            tt *= rd; ksum[1] += tt; rd *= EM4;
            tt *= rd; ksum[0] += tt;
            ksum[10] += (s > 0.995f) ? 1.f : 0.f;
        }
    }
    #pragma unroll
    for (int k = 0; k < KNUM; ++k) {
        ksum[k] += __shfl_xor(ksum[k], 16);
        ksum[k] += __shfl_xor(ksum[k], 32);
    }
    if (quad == 0) {
        #pragma unroll
        for (int k = 0; k < KNUM; ++k)
            atomicAdd(&stot[mtbase + l15][k], ksum[k]);
    }
}

// Legacy kernel, kept as the small-workspace fallback (instantiated <false>).
template<bool PRE>
__global__ __launch_bounds__(256, 4)
void knrm_pair(const float* __restrict__ emb,
               const ushort* __restrict__ ebf,
               const float* __restrict__ inorm,
               const float* __restrict__ mlp_w,
               const int* __restrict__ q1, const int* __restrict__ d1,
               const int* __restrict__ q2, const int* __restrict__ d2,
               float* __restrict__ logits)
{
    const int b    = blockIdx.x;
    const int pair = blockIdx.y;
    const int t    = threadIdx.x;
    const int w    = t >> 6;
    const int l15  = t & 15;
    const int quad = (t & 63) >> 4;

    const int* __restrict__ qry = (pair == 0 ? q1 : q2) + b * QLEN;
    const int* __restrict__ doc = (pair == 0 ? d1 : d2) + b * DLEN;

    __shared__ __align__(16) float s_sim[4 * SHALF];
    __shared__ float s_tot[QLEN][12];

    #pragma unroll
    for (int i = t; i < QLEN * 12; i += 256) ((float*)s_tot)[i] = 0.f;
    __syncthreads();

    const int qid0 = qry[l15], qid1 = qry[l15 + 16];
    int did[4];
    #pragma unroll
    for (int nt = 0; nt < 4; ++nt) did[nt] = doc[(w * 4 + nt) * 16 + l15];

    f32x4 acc[2][4];
    #pragma unroll
    for (int mt = 0; mt < 2; ++mt)
        #pragma unroll
        for (int nt = 0; nt < 4; ++nt)
            acc[mt][nt] = (f32x4){0.f, 0.f, 0.f, 0.f};

    float idn[4], riq[2][4];
    float* wtile = s_sim + w * SHALF;

    if (PRE) {
        const ushort* qp0 = ebf + (size_t)qid0 * EMBED + quad * 8;
        const ushort* qp1 = ebf + (size_t)qid1 * EMBED + quad * 8;
        #pragma unroll
        for (int kk = 0; kk < 4; ++kk) {
            const bf16x8 a0 = *((const bf16x8*)(qp0 + kk * 32));
            const bf16x8 a1 = *((const bf16x8*)(qp1 + kk * 32));
            #pragma unroll
            for (int nt = 0; nt < 4; ++nt) {
                const bf16x8 bb = *((const bf16x8*)(ebf + (size_t)did[nt] * EMBED + quad * 8 + kk * 32));
                acc[0][nt] = __builtin_amdgcn_mfma_f32_16x16x32_bf16(a0, bb, acc[0][nt], 0, 0, 0);
                acc[1][nt] = __builtin_amdgcn_mfma_f32_16x16x32_bf16(a1, bb, acc[1][nt], 0, 0, 0);
            }
        }
        #pragma unroll
        for (int nt = 0; nt < 4; ++nt) idn[nt] = inorm[did[nt]];
        #pragma unroll
        for (int r = 0; r < 4; ++r) {
            riq[0][r] = inorm[qry[quad * 4 + r]];
            riq[1][r] = inorm[qry[16 + quad * 4 + r]];
        }
    } else {
        float qn2[2] = {0.f, 0.f}, dn2[4] = {0.f, 0.f, 0.f, 0.f};
        const float* qp0 = emb + (size_t)qid0 * EMBED + quad * 8;
        const float* qp1 = emb + (size_t)qid1 * EMBED + quad * 8;
        #pragma unroll
        for (int kk = 0; kk < 4; ++kk) {
            const bf16x8 a0 = cvt8(qp0 + kk * 32, qn2[0]);
            const bf16x8 a1 = cvt8(qp1 + kk * 32, qn2[1]);
            #pragma unroll
            for (int nt = 0; nt < 4; ++nt) {
                const bf16x8 bb = cvt8(emb + (size_t)did[nt] * EMBED + quad * 8 + kk * 32, dn2[nt]);
                acc[0][nt] = __builtin_amdgcn_mfma_f32_16x16x32_bf16(a0, bb, acc[0][nt], 0, 0, 0);
                acc[1][nt] = __builtin_amdgcn_mfma_f32_16x16x32_bf16(a1, bb, acc[1][nt], 0, 0, 0);
            }
        }
        #pragma unroll
        for (int i = 0; i < 2; ++i) {
            qn2[i] += __shfl_xor(qn2[i], 16);
            qn2[i] += __shfl_xor(qn2[i], 32);
        }
        #pragma unroll
        for (int nt = 0; nt < 4; ++nt) {
            dn2[nt] += __shfl_xor(dn2[nt], 16);
            dn2[nt] += __shfl_xor(dn2[nt], 32);
            idn[nt] = __builtin_amdgcn_rsqf(dn2[nt]);
        }
        #pragma unroll
        for (int r = 0; r < 4; ++r) {
            riq[0][r] = __builtin_amdgcn_rsqf(__shfl(qn2[0], quad * 4 + r));
            riq[1][r] = __builtin_amdgcn_rsqf(__shfl(qn2[1], quad * 4 + r));
        }
    }

    pool_half(wtile, acc[0], riq[0], idn, s_tot, 0,  l15, quad);
    pool_half(wtile, acc[1], riq[1], idn, s_tot, 16, l15, quad);
    __syncthreads();

    if (t < QLEN) {
        float c = 0.f;
        #pragma unroll
        for (int k = 0; k < KNUM; ++k) c += mlp_w[k] * log1pf(s_tot[t][k]);
        #pragma unroll
        for (int mm = 1; mm < 32; mm <<= 1) c += __shfl_xor(c, mm);
        if (t == 0) logits[pair * NB + b] = c;
    }
}

__global__ __launch_bounds__(256)
void knrm_combine(const float* __restrict__ logits, float* __restrict__ out)
{
    const int i = blockIdx.x * blockDim.x + threadIdx.x;
    if (i < NB) {
        const float d = logits[i] - logits[NB + i];
        out[i] = 1.f / (1.f + __expf(-d));
    }
}

extern "C" void kernel_launch(void* const* d_in, const int* in_sizes, int n_in,
                              void* d_out, int out_size, void* d_ws, size_t ws_size,
                              hipStream_t stream)
{
    const float* emb   = (const float*)d_in[0];
    const float* mlp_w = (const float*)d_in[1];
    // mlp_b (d_in[2]) unused: cancels in logits1 - logits2
    const int* q1 = (const int*)d_in[3];
    const int* d1 = (const int*)d_in[4];
    const int* q2 = (const int*)d_in[5];
    const int* d2 = (const int*)d_in[6];

    float* out = (float*)d_out;

    const size_t need = 2 * NB * 4                       // logits
                      + (size_t)VOCAB * 4                // inorm
                      + (size_t)VOCAB * EMBED * 2 + 256; // bf16 table
    if (ws_size >= need) {
        float*  logits = (float*)d_ws;
        float*  inorm  = logits + 2 * NB;
        ushort* ebf    = (ushort*)(inorm + VOCAB);
        cvt_table<<<VOCAB / 8, 256, 0, stream>>>(emb, ebf, inorm);
        knrm_pair2<<<dim3(NB, 2), 128, 0, stream>>>(ebf, inorm, mlp_w,
                                                    q1, d1, q2, d2, logits);
    } else {
        float* logits = (float*)d_ws;
        knrm_pair<false><<<dim3(NB, 2), 256, 0, stream>>>(emb, nullptr, nullptr, mlp_w,
                                                          q1, d1, q2, d2, logits);
    }
    knrm_combine<<<(NB + 255) / 256, 256, 0, stream>>>((float*)d_ws, out);
}

// Round 2
// 173.313 us; speedup vs baseline: 1.0807x; 1.0807x over previous
//
#include <hip/hip_runtime.h>
#include <math.h>
#include <stdint.h>

#define VOCAB 100000
#define NB    1024
#define QLEN  32
#define DLEN  256
#define EMBED 128
#define KNUM  11

typedef __attribute__((ext_vector_type(8))) short bf16x8;   // 8 bf16 = 4 VGPRs
typedef __attribute__((ext_vector_type(4))) float f32x4;

// Gaussian chain: mus -0.9..0.9 step 0.2 (sigma 0.1) + exact mu=1 sigma=.001
#define HALF_L2E 0.7213475204444817f   // 0.5*log2(e)
#define TWO_L2E  2.8853900817779268f   // 2*log2(e)
#define EM4      0.018315638888734179f // e^-4

// Legacy fallback tile constants
#define SSTR  68
#define SHALF (16 * SSTR)

// ---------- prepass: fp32 table -> bf16 table + bf16-consistent inv-norms ----
__global__ __launch_bounds__(256)
void cvt_table(const float* __restrict__ emb, ushort* __restrict__ ebf,
               float* __restrict__ inorm)
{
    const int row = blockIdx.x * 8 + (threadIdx.x >> 5);
    const int l32 = threadIdx.x & 31;
    const float4 v = *((const float4*)(emb + (size_t)row * EMBED) + l32);
    union { float f; unsigned u; } x0, x1, x2, x3;
    x0.f = v.x; x1.f = v.y; x2.f = v.z; x3.f = v.w;
    const unsigned r0 = x0.u + 0x8000u, r1 = x1.u + 0x8000u;  // round-half-up
    const unsigned r2 = x2.u + 0x8000u, r3 = x3.u + 0x8000u;
    uint2 packed;
    packed.x = (r0 >> 16) | (r1 & 0xFFFF0000u);
    packed.y = (r2 >> 16) | (r3 & 0xFFFF0000u);
    *((uint2*)(ebf + (size_t)row * EMBED) + l32) = packed;
    x0.u = r0 & 0xFFFF0000u; x1.u = r1 & 0xFFFF0000u;
    x2.u = r2 & 0xFFFF0000u; x3.u = r3 & 0xFFFF0000u;
    float n = x0.f * x0.f + x1.f * x1.f + x2.f * x2.f + x3.f * x3.f;
    #pragma unroll
    for (int m = 1; m < 32; m <<= 1) n += __shfl_xor(n, m);
    if (l32 == 0) inorm[row] = __builtin_amdgcn_rsqf(n);
}

// ---------------------------------------------------------------------------
// global_load_lds helper: 16B per lane, per-lane scattered GLOBAL address,
// wave-uniform LDS base (HW writes base + lane*16).
__device__ __forceinline__ void gl_lds16(const ushort* g, ushort* lds)
{
    auto gp = reinterpret_cast<const __attribute__((address_space(1))) void*>(
        reinterpret_cast<uintptr_t>(g));
    auto lp = reinterpret_cast<__attribute__((address_space(3))) void*>(
        static_cast<unsigned>(reinterpret_cast<uintptr_t>(lds)));
    __builtin_amdgcn_global_load_lds(gp, lp, 16, 0, 0);
}

#define WAITV(n) asm volatile("s_waitcnt vmcnt(" #n ")" ::: "memory")

// ---------------------------------------------------------------------------
// 2 waves/block (wave w owns q rows w*16..w*16+15). Doc rows staged to LDS
// via global_load_lds in 16-row (4KB) chunks, layout [buf][kk][lane][16B]
// (DMA write AND ds_read_b128 both linear). 4-buffer rotation, 3 chunks in
// flight, counted vmcnt(4) (never 0 mid-loop), 1 raw s_barrier per chunk.
//
// Round-2 fix: NO runtime-indexed per-thread arrays (round-1 spilled dcid[16]/
// idnv[16] to scratch: 117MB WRITE_SIZE). Doc ids + inv-norms live in LDS
// (s_ids/s_idn, runtime-indexable). Pooling works directly on the MFMA C
// layout with ksum[4][KNUM] (statically indexed); the per-q-row doc-sum
// reduction happens ONCE at block end via shfl, not per chunk. No s_sim.
//
// Buffer-reuse safety: STAGE(c=nt+3) at iter nt writes buf (nt-1)&3; every
// wave's chunk nt-1 reads were consumed (lgkm-waited) before it reached the
// iter-nt barrier, and the STAGE is issued after that barrier.
__global__ __launch_bounds__(128, 4)
void knrm_pair2(const ushort* __restrict__ ebf,
                const float* __restrict__ inorm,
                const float* __restrict__ mlp_w,
                const int* __restrict__ q1, const int* __restrict__ d1,
                const int* __restrict__ q2, const int* __restrict__ d2,
                float* __restrict__ logits)
{
    const int b    = blockIdx.x;
    const int pair = blockIdx.y;
    const int t    = threadIdx.x;
    const int w    = t >> 6;        // wave id = q half
    const int l    = t & 63;
    const int l15  = l & 15;
    const int quad = l >> 4;

    const int* __restrict__ qry = (pair == 0 ? q1 : q2) + b * QLEN;
    const int* __restrict__ doc = (pair == 0 ? d1 : d2) + b * DLEN;

    __shared__ __align__(16) ushort s_doc[4][4][64][8];  // 16 KB: [buf][kk][lane][16B]
    __shared__ int   s_ids[DLEN];                        // 1 KB
    __shared__ float s_idn[DLEN];                        // 1 KB
    __shared__ float s_part[2];

    // ---- doc metadata -> LDS (each thread handles 2 of the 256 rows) ----
    #pragma unroll
    for (int i = t; i < DLEN; i += 128) {
        const int id = doc[i];
        s_ids[i] = id;
        s_idn[i] = inorm[id];
    }

    // ---- q-side loop invariants (registers, all statically indexed) ----
    const int qid = qry[w * 16 + l15];
    float riqw[4];
    #pragma unroll
    for (int r = 0; r < 4; ++r) riqw[r] = inorm[qry[w * 16 + quad * 4 + r]];
    bf16x8 aq[4];                                  // A-frags: row qry[w*16+l15]
    {
        const ushort* qp = ebf + (size_t)qid * EMBED + quad * 8;
        #pragma unroll
        for (int kk = 0; kk < 4; ++kk) aq[kk] = *(const bf16x8*)(qp + kk * 32);
    }

    WAITV(0);                        // drain ALL prologue vmem: exact counting
    __syncthreads();                 // s_ids/s_idn visible block-wide

    // ---- staging: wave w DMAs kk = 2w, 2w+1 of each chunk (2 instr/chunk) ----
    #define STAGE(c)                                                              \
    {                                                                             \
        const int did = s_ids[(c) * 16 + l15];                                    \
        const ushort* gbase = ebf + (size_t)did * EMBED + quad * 8;               \
        gl_lds16(gbase + (2 * w) * 32,     &s_doc[(c) & 3][2 * w][0][0]);         \
        gl_lds16(gbase + (2 * w + 1) * 32, &s_doc[(c) & 3][2 * w + 1][0][0]);     \
    }

    STAGE(0); STAGE(1); STAGE(2);

    float ksum[4][KNUM];             // [row-slot r][kernel] — static indices only
    #pragma unroll
    for (int r = 0; r < 4; ++r)
        #pragma unroll
        for (int k = 0; k < KNUM; ++k) ksum[r][k] = 0.f;

    for (int nt = 0; nt < 16; ++nt) {
        // own chunk-nt stages retired (outstanding: <=2 newest chunks = 4 instr)
        if      (nt < 14)  WAITV(4);
        else if (nt == 14) WAITV(2);
        else               WAITV(0);
        __builtin_amdgcn_s_barrier();            // both waves' chunk nt in LDS
        __builtin_amdgcn_sched_barrier(0);       // nothing crosses the barrier

        if (nt < 13) STAGE(nt + 3);

        // ---- MFMA: 16 q-rows x 16 doc-cols x K=128 ----
        f32x4 acc = {0.f, 0.f, 0.f, 0.f};
        #pragma unroll
        for (int kk = 0; kk < 4; ++kk) {
            const bf16x8 bb = *(const bf16x8*)&s_doc[nt & 3][kk][l][0];
            acc = __builtin_amdgcn_mfma_f32_16x16x32_bf16(aq[kk], bb, acc, 0, 0, 0);
        }

        // ---- pool in MFMA layout: lane owns (row quad*4+r, col l15) ----
        const float idn_c = s_idn[nt * 16 + l15];
        #pragma unroll
        for (int r = 0; r < 4; ++r) {
            const float s  = acc[r] * riqw[r] * idn_c;
            const float z  = fmaf(s, 10.f, -1.f);
            const float e0 = exp2f(-HALF_L2E * (z * z));
            float ru = exp2f(fmaf(z,  TWO_L2E, -TWO_L2E));
            float rd = exp2f(fmaf(z, -TWO_L2E, -TWO_L2E));
            ksum[r][5] += e0;
            float tt = e0;
            tt *= ru; ksum[r][6] += tt; ru *= EM4;
            tt *= ru; ksum[r][7] += tt; ru *= EM4;
            tt *= ru; ksum[r][8] += tt; ru *= EM4;
            tt *= ru; ksum[r][9] += tt;
            tt = e0;
            tt *= rd; ksum[r][4] += tt; rd *= EM4;
            tt *= rd; ksum[r][3] += tt; rd *= EM4;
            tt *= rd; ksum[r][2] += tt; rd *= EM4;
            tt *= rd; ksum[r][1] += tt; rd *= EM4;
            tt *= rd; ksum[r][0] += tt;
            // exact kernel (sigma=.001): ==1 iff token match (bf16 self-sim
            // 1+-3e-6; non-match needs cos>0.995 ~ 11 sigma)
            ksum[r][10] += (s > 0.995f) ? 1.f : 0.f;
        }
    }
    #undef STAGE

    // ---- per-q-row doc-sum: reduce across the 16 lanes of each quad group ----
    #pragma unroll
    for (int r = 0; r < 4; ++r)
        #pragma unroll
        for (int k = 0; k < KNUM; ++k) {
            float v = ksum[r][k];
            v += __shfl_xor(v, 1);
            v += __shfl_xor(v, 2);
            v += __shfl_xor(v, 4);
            v += __shfl_xor(v, 8);
            ksum[r][k] = v;
        }

    float wk[KNUM];
    #pragma unroll
    for (int k = 0; k < KNUM; ++k) wk[k] = mlp_w[k];

    float c = 0.f;
    #pragma unroll
    for (int r = 0; r < 4; ++r)
        #pragma unroll
        for (int k = 0; k < KNUM; ++k) c += wk[k] * log1pf(ksum[r][k]);
    c += __shfl_xor(c, 16);          // combine the 4 quad groups (rows 0..15)
    c += __shfl_xor(c, 32);
    if (l == 0) s_part[w] = c;
    __syncthreads();
    if (t == 0) logits[pair * NB + b] = s_part[0] + s_part[1]; // mlp bias cancels
}

// ---------------------------------------------------------------------------
// fallback helper: fp32 -> bf16 frag + norm of rounded values
__device__ __forceinline__ bf16x8 cvt8(const float* p, float& nacc)
{
    uint4 a = *((const uint4*)p);
    uint4 b = *((const uint4*)(p + 4));
    unsigned u[8] = {a.x, a.y, a.z, a.w, b.x, b.y, b.z, b.w};
    bf16x8 r;
    #pragma unroll
    for (int i = 0; i < 8; ++i) {
        const unsigned q = u[i] + 0x8000u;
        r[i] = (short)(q >> 16);
        union { unsigned uu; float ff; } g; g.uu = q & 0xFFFF0000u;
        nacc = fmaf(g.ff, g.ff, nacc);
    }
    return r;
}

__device__ __forceinline__ void pool_half(float* __restrict__ wtile,
                                          const f32x4* __restrict__ a,
                                          const float* __restrict__ riq,
                                          const float* __restrict__ idn,
                                          float (*__restrict__ stot)[12],
                                          int mtbase, int l15, int quad)
{
    #pragma unroll
    for (int nt = 0; nt < 4; ++nt)
        #pragma unroll
        for (int r = 0; r < 4; ++r)
            wtile[(quad * 4 + r) * SSTR + nt * 16 + l15] = a[nt][r] * riq[r] * idn[nt];

    const float* rp = wtile + l15 * SSTR + quad * 16;
    float ksum[KNUM];
    #pragma unroll
    for (int k = 0; k < KNUM; ++k) ksum[k] = 0.f;

    #pragma unroll
    for (int i = 0; i < 4; ++i) {
        const f32x4 sv = *((const f32x4*)(rp + 4 * i));
        #pragma unroll
        for (int e = 0; e < 4; ++e) {
            const float s  = sv[e];
            const float z  = fmaf(s, 10.f, -1.f);
            const float e0 = exp2f(-HALF_L2E * (z * z));
            float ru = exp2f(fmaf(z,  TWO_L2E, -TWO_L2E));
            float rd = exp2f(fmaf(z, -TWO_L2E, -TWO_L2E));
            ksum[5] += e0;
            float tt = e0;
            tt *= ru; ksum[6] += tt; ru *= EM4;
            tt *= ru; ksum[7] += tt; ru *= EM4;
            tt *= ru; ksum[8] += tt; ru *= EM4;
            tt *= ru; ksum[9] += tt;
            tt = e0;
            tt *= rd; ksum[4] += tt; rd *= EM4;
            tt *= rd; ksum[3] += tt; rd *= EM4;
            tt *= rd; ksum[2] += tt; rd *= EM4;
            tt *= rd; ksum[1] += tt; rd *= EM4;
            tt *= rd; ksum[0] += tt;
            ksum[10] += (s > 0.995f) ? 1.f : 0.f;
        }
    }
    #pragma unroll
    for (int k = 0; k < KNUM; ++k) {
        ksum[k] += __shfl_xor(ksum[k], 16);
        ksum[k] += __shfl_xor(ksum[k], 32);
    }
    if (quad == 0) {
        #pragma unroll
        for (int k = 0; k < KNUM; ++k)
            atomicAdd(&stot[mtbase + l15][k], ksum[k]);
    }
}

// Legacy kernel, kept as the small-workspace fallback (instantiated <false>).
template<bool PRE>
__global__ __launch_bounds__(256, 4)
void knrm_pair(const float* __restrict__ emb,
               const ushort* __restrict__ ebf,
               const float* __restrict__ inorm,
               const float* __restrict__ mlp_w,
               const int* __restrict__ q1, const int* __restrict__ d1,
               const int* __restrict__ q2, const int* __restrict__ d2,
               float* __restrict__ logits)
{
    const int b    = blockIdx.x;
    const int pair = blockIdx.y;
    const int t    = threadIdx.x;
    const int w    = t >> 6;
    const int l15  = t & 15;
    const int quad = (t & 63) >> 4;

    const int* __restrict__ qry = (pair == 0 ? q1 : q2) + b * QLEN;
    const int* __restrict__ doc = (pair == 0 ? d1 : d2) + b * DLEN;

    __shared__ __align__(16) float s_sim[4 * SHALF];
    __shared__ float s_tot[QLEN][12];

    #pragma unroll
    for (int i = t; i < QLEN * 12; i += 256) ((float*)s_tot)[i] = 0.f;
    __syncthreads();

    const int qid0 = qry[l15], qid1 = qry[l15 + 16];
    int did[4];
    #pragma unroll
    for (int nt = 0; nt < 4; ++nt) did[nt] = doc[(w * 4 + nt) * 16 + l15];

    f32x4 acc[2][4];
    #pragma unroll
    for (int mt = 0; mt < 2; ++mt)
        #pragma unroll
        for (int nt = 0; nt < 4; ++nt)
            acc[mt][nt] = (f32x4){0.f, 0.f, 0.f, 0.f};

    float idn[4], riq[2][4];
    float* wtile = s_sim + w * SHALF;

    if (PRE) {
        const ushort* qp0 = ebf + (size_t)qid0 * EMBED + quad * 8;
        const ushort* qp1 = ebf + (size_t)qid1 * EMBED + quad * 8;
        #pragma unroll
        for (int kk = 0; kk < 4; ++kk) {
            const bf16x8 a0 = *((const bf16x8*)(qp0 + kk * 32));
            const bf16x8 a1 = *((const bf16x8*)(qp1 + kk * 32));
            #pragma unroll
            for (int nt = 0; nt < 4; ++nt) {
                const bf16x8 bb = *((const bf16x8*)(ebf + (size_t)did[nt] * EMBED + quad * 8 + kk * 32));
                acc[0][nt] = __builtin_amdgcn_mfma_f32_16x16x32_bf16(a0, bb, acc[0][nt], 0, 0, 0);
                acc[1][nt] = __builtin_amdgcn_mfma_f32_16x16x32_bf16(a1, bb, acc[1][nt], 0, 0, 0);
            }
        }
        #pragma unroll
        for (int nt = 0; nt < 4; ++nt) idn[nt] = inorm[did[nt]];
        #pragma unroll
        for (int r = 0; r < 4; ++r) {
            riq[0][r] = inorm[qry[quad * 4 + r]];
            riq[1][r] = inorm[qry[16 + quad * 4 + r]];
        }
    } else {
        float qn2[2] = {0.f, 0.f}, dn2[4] = {0.f, 0.f, 0.f, 0.f};
        const float* qp0 = emb + (size_t)qid0 * EMBED + quad * 8;
        const float* qp1 = emb + (size_t)qid1 * EMBED + quad * 8;
        #pragma unroll
        for (int kk = 0; kk < 4; ++kk) {
            const bf16x8 a0 = cvt8(qp0 + kk * 32, qn2[0]);
            const bf16x8 a1 = cvt8(qp1 + kk * 32, qn2[1]);
            #pragma unroll
            for (int nt = 0; nt < 4; ++nt) {
                const bf16x8 bb = cvt8(emb + (size_t)did[nt] * EMBED + quad * 8 + kk * 32, dn2[nt]);
                acc[0][nt] = __builtin_amdgcn_mfma_f32_16x16x32_bf16(a0, bb, acc[0][nt], 0, 0, 0);
                acc[1][nt] = __builtin_amdgcn_mfma_f32_16x16x32_bf16(a1, bb, acc[1][nt], 0, 0, 0);
            }
        }
        #pragma unroll
        for (int i = 0; i < 2; ++i) {
            qn2[i] += __shfl_xor(qn2[i], 16);
            qn2[i] += __shfl_xor(qn2[i], 32);
        }
        #pragma unroll
        for (int nt = 0; nt < 4; ++nt) {
            dn2[nt] += __shfl_xor(dn2[nt], 16);
            dn2[nt] += __shfl_xor(dn2[nt], 32);
            idn[nt] = __builtin_amdgcn_rsqf(dn2[nt]);
        }
        #pragma unroll
        for (int r = 0; r < 4; ++r) {
            riq[0][r] = __builtin_amdgcn_rsqf(__shfl(qn2[0], quad * 4 + r));
            riq[1][r] = __builtin_amdgcn_rsqf(__shfl(qn2[1], quad * 4 + r));
        }
    }

    pool_half(wtile, acc[0], riq[0], idn, s_tot, 0,  l15, quad);
    pool_half(wtile, acc[1], riq[1], idn, s_tot, 16, l15, quad);
    __syncthreads();

    if (t < QLEN) {
        float c = 0.f;
        #pragma unroll
        for (int k = 0; k < KNUM; ++k) c += mlp_w[k] * log1pf(s_tot[t][k]);
        #pragma unroll
        for (int mm = 1; mm < 32; mm <<= 1) c += __shfl_xor(c, mm);
        if (t == 0) logits[pair * NB + b] = c;
    }
}

__global__ __launch_bounds__(256)
void knrm_combine(const float* __restrict__ logits, float* __restrict__ out)
{
    const int i = blockIdx.x * blockDim.x + threadIdx.x;
    if (i < NB) {
        const float d = logits[i] - logits[NB + i];
        out[i] = 1.f / (1.f + __expf(-d));
    }
}

extern "C" void kernel_launch(void* const* d_in, const int* in_sizes, int n_in,
                              void* d_out, int out_size, void* d_ws, size_t ws_size,
                              hipStream_t stream)
{
    const float* emb   = (const float*)d_in[0];
    const float* mlp_w = (const float*)d_in[1];
    // mlp_b (d_in[2]) unused: cancels in logits1 - logits2
    const int* q1 = (const int*)d_in[3];
    const int* d1 = (const int*)d_in[4];
    const int* q2 = (const int*)d_in[5];
    const int* d2 = (const int*)d_in[6];

    float* out = (float*)d_out;

    const size_t need = 2 * NB * 4                       // logits
                      + (size_t)VOCAB * 4                // inorm
                      + (size_t)VOCAB * EMBED * 2 + 256; // bf16 table
    if (ws_size >= need) {
        float*  logits = (float*)d_ws;
        float*  inorm  = logits + 2 * NB;
        ushort* ebf    = (ushort*)(inorm + VOCAB);
        cvt_table<<<VOCAB / 8, 256, 0, stream>>>(emb, ebf, inorm);
        knrm_pair2<<<dim3(NB, 2), 128, 0, stream>>>(ebf, inorm, mlp_w,
                                                    q1, d1, q2, d2, logits);
    } else {
        float* logits = (float*)d_ws;
        knrm_pair<false><<<dim3(NB, 2), 256, 0, stream>>>(emb, nullptr, nullptr, mlp_w,
                                                          q1, d1, q2, d2, logits);
    }
    knrm_combine<<<(NB + 255) / 256, 256, 0, stream>>>((float*)d_ws, out);
}

// Round 3
// 167.324 us; speedup vs baseline: 1.1194x; 1.0358x over previous
//
#include <hip/hip_runtime.h>
#include <math.h>
#include <stdint.h>

#define VOCAB 100000
#define NB    1024
#define QLEN  32
#define DLEN  256
#define EMBED 128
#define KNUM  11

typedef __attribute__((ext_vector_type(8))) short bf16x8;   // 8 bf16 = 4 VGPRs
typedef __attribute__((ext_vector_type(4))) float f32x4;

// Gaussian chain: mus -0.9..0.9 step 0.2 (sigma 0.1) + exact mu=1 sigma=.001
#define HALF_L2E 0.7213475204444817f   // 0.5*log2(e)
#define TWO_L2E  2.8853900817779268f   // 2*log2(e)
#define EM4      0.018315638888734179f // e^-4

// Legacy fallback tile constants
#define SSTR  68
#define SHALF (16 * SSTR)

// ---------- prepass: fp32 table -> bf16 table + bf16-consistent inv-norms ----
__global__ __launch_bounds__(256)
void cvt_table(const float* __restrict__ emb, ushort* __restrict__ ebf,
               float* __restrict__ inorm)
{
    const int row = blockIdx.x * 8 + (threadIdx.x >> 5);
    const int l32 = threadIdx.x & 31;
    const float4 v = *((const float4*)(emb + (size_t)row * EMBED) + l32);
    union { float f; unsigned u; } x0, x1, x2, x3;
    x0.f = v.x; x1.f = v.y; x2.f = v.z; x3.f = v.w;
    const unsigned r0 = x0.u + 0x8000u, r1 = x1.u + 0x8000u;  // round-half-up
    const unsigned r2 = x2.u + 0x8000u, r3 = x3.u + 0x8000u;
    uint2 packed;
    packed.x = (r0 >> 16) | (r1 & 0xFFFF0000u);
    packed.y = (r2 >> 16) | (r3 & 0xFFFF0000u);
    *((uint2*)(ebf + (size_t)row * EMBED) + l32) = packed;
    x0.u = r0 & 0xFFFF0000u; x1.u = r1 & 0xFFFF0000u;
    x2.u = r2 & 0xFFFF0000u; x3.u = r3 & 0xFFFF0000u;
    float n = x0.f * x0.f + x1.f * x1.f + x2.f * x2.f + x3.f * x3.f;
    #pragma unroll
    for (int m = 1; m < 32; m <<= 1) n += __shfl_xor(n, m);
    if (l32 == 0) inorm[row] = __builtin_amdgcn_rsqf(n);
}

// ---------------------------------------------------------------------------
// Round-3 main kernel: legacy shape (4 waves, 256 thr, wave w owns doc tiles
// w*4..w*4+3; acc[2][4] covers both q halves) BUT with ALL 24 row-gathers per
// wave hoisted into named registers before the first MFMA (launch_bounds
// (256,3), est ~150 VGPR, no spill). This is the MLP experiment: in-flight
// gathers/CU rises ~5x vs the 52-VGPR legacy schedule.
// Pooling happens directly in MFMA C-layout in registers (proven in round 2;
// lane owns rows quad*4+r, col l15 of each tile): no s_sim LDS, fewer atomics.
__global__ __launch_bounds__(256, 3)
void knrm_pair3(const ushort* __restrict__ ebf,
                const float* __restrict__ inorm,
                const float* __restrict__ mlp_w,
                const int* __restrict__ q1, const int* __restrict__ d1,
                const int* __restrict__ q2, const int* __restrict__ d2,
                float* __restrict__ logits)
{
    const int b    = blockIdx.x;
    const int pair = blockIdx.y;
    const int t    = threadIdx.x;
    const int w    = t >> 6;        // wave id: doc tiles w*4..w*4+3
    const int l    = t & 63;
    const int l15  = l & 15;
    const int quad = l >> 4;

    const int* __restrict__ qry = (pair == 0 ? q1 : q2) + b * QLEN;
    const int* __restrict__ doc = (pair == 0 ? d1 : d2) + b * DLEN;

    __shared__ float s_tot[QLEN][12];                  // 1.5 KB only
    #pragma unroll
    for (int i = t; i < QLEN * 12; i += 256) ((float*)s_tot)[i] = 0.f;

    // ---- ids (independent 4B loads, oldest) ----
    const int qid0 = qry[l15], qid1 = qry[l15 + 16];
    int did[4];
    #pragma unroll
    for (int j = 0; j < 4; ++j) did[j] = doc[(w * 4 + j) * 16 + l15];

    // ---- FULL prefetch: 8 q-frags + 16 doc-frags, all issued before MFMA ----
    bf16x8 aq0[4], aq1[4], bb[4][4];
    {
        const ushort* qp0 = ebf + (size_t)qid0 * EMBED + quad * 8;
        const ushort* qp1 = ebf + (size_t)qid1 * EMBED + quad * 8;
        #pragma unroll
        for (int kk = 0; kk < 4; ++kk) {
            aq0[kk] = *(const bf16x8*)(qp0 + kk * 32);
            aq1[kk] = *(const bf16x8*)(qp1 + kk * 32);
        }
        #pragma unroll
        for (int j = 0; j < 4; ++j) {
            const ushort* dp = ebf + (size_t)did[j] * EMBED + quad * 8;
            #pragma unroll
            for (int kk = 0; kk < 4; ++kk)
                bb[j][kk] = *(const bf16x8*)(dp + kk * 32);
        }
    }
    // norms (consumed only in pooling -> latency fully hidden)
    float idn[4];
    #pragma unroll
    for (int j = 0; j < 4; ++j) idn[j] = inorm[did[j]];
    float riq[2][4];
    #pragma unroll
    for (int r = 0; r < 4; ++r) {
        riq[0][r] = inorm[qry[quad * 4 + r]];
        riq[1][r] = inorm[qry[16 + quad * 4 + r]];
    }

    // ---- MFMA: first MFMA waits only for its own frags; rest stay in flight ----
    f32x4 acc[2][4];
    #pragma unroll
    for (int mt = 0; mt < 2; ++mt)
        #pragma unroll
        for (int j = 0; j < 4; ++j)
            acc[mt][j] = (f32x4){0.f, 0.f, 0.f, 0.f};
    #pragma unroll
    for (int kk = 0; kk < 4; ++kk)
        #pragma unroll
        for (int j = 0; j < 4; ++j) {
            acc[0][j] = __builtin_amdgcn_mfma_f32_16x16x32_bf16(aq0[kk], bb[j][kk], acc[0][j], 0, 0, 0);
            acc[1][j] = __builtin_amdgcn_mfma_f32_16x16x32_bf16(aq1[kk], bb[j][kk], acc[1][j], 0, 0, 0);
        }

    __syncthreads();        // s_tot zeros visible before any atomic below

    // ---- pool in MFMA layout: lane owns (row quad*4+r, col l15) of each tile ----
    #pragma unroll
    for (int mt = 0; mt < 2; ++mt) {
        float ksum[4][KNUM];
        #pragma unroll
        for (int r = 0; r < 4; ++r)
            #pragma unroll
            for (int k = 0; k < KNUM; ++k) ksum[r][k] = 0.f;

        #pragma unroll
        for (int j = 0; j < 4; ++j) {
            const float idn_c = idn[j];
            #pragma unroll
            for (int r = 0; r < 4; ++r) {
                const float s  = acc[mt][j][r] * riq[mt][r] * idn_c;
                const float z  = fmaf(s, 10.f, -1.f);
                const float e0 = exp2f(-HALF_L2E * (z * z));
                float ru = exp2f(fmaf(z,  TWO_L2E, -TWO_L2E));
                float rd = exp2f(fmaf(z, -TWO_L2E, -TWO_L2E));
                ksum[r][5] += e0;
                float tt = e0;
                tt *= ru; ksum[r][6] += tt; ru *= EM4;
                tt *= ru; ksum[r][7] += tt; ru *= EM4;
                tt *= ru; ksum[r][8] += tt; ru *= EM4;
                tt *= ru; ksum[r][9] += tt;
                tt = e0;
                tt *= rd; ksum[r][4] += tt; rd *= EM4;
                tt *= rd; ksum[r][3] += tt; rd *= EM4;
                tt *= rd; ksum[r][2] += tt; rd *= EM4;
                tt *= rd; ksum[r][1] += tt; rd *= EM4;
                tt *= rd; ksum[r][0] += tt;
                // exact kernel (sigma=.001): ==1 iff token match (bf16 self-sim
                // 1+-3e-6; non-match needs cos>0.995 ~ 11 sigma)
                ksum[r][10] += (s > 0.995f) ? 1.f : 0.f;
            }
        }
        // reduce over the 16 cols (lanes differing in bits 0-3), then one
        // atomic per (row,k) from the l15==0 lane of each quad group
        #pragma unroll
        for (int r = 0; r < 4; ++r)
            #pragma unroll
            for (int k = 0; k < KNUM; ++k) {
                float v = ksum[r][k];
                v += __shfl_xor(v, 1);
                v += __shfl_xor(v, 2);
                v += __shfl_xor(v, 4);
                v += __shfl_xor(v, 8);
                if (l15 == 0)
                    atomicAdd(&s_tot[mt * 16 + quad * 4 + r][k], v);
            }
    }
    __syncthreads();

    if (t < QLEN) {
        float c = 0.f;
        #pragma unroll
        for (int k = 0; k < KNUM; ++k) c += mlp_w[k] * log1pf(s_tot[t][k]);
        #pragma unroll
        for (int mm = 1; mm < 32; mm <<= 1) c += __shfl_xor(c, mm);
        if (t == 0) logits[pair * NB + b] = c;   // mlp bias cancels in l1-l2
    }
}

// ---------------------------------------------------------------------------
// fallback helper: fp32 -> bf16 frag + norm of rounded values
__device__ __forceinline__ bf16x8 cvt8(const float* p, float& nacc)
{
    uint4 a = *((const uint4*)p);
    uint4 b = *((const uint4*)(p + 4));
    unsigned u[8] = {a.x, a.y, a.z, a.w, b.x, b.y, b.z, b.w};
    bf16x8 r;
    #pragma unroll
    for (int i = 0; i < 8; ++i) {
        const unsigned q = u[i] + 0x8000u;
        r[i] = (short)(q >> 16);
        union { unsigned uu; float ff; } g; g.uu = q & 0xFFFF0000u;
        nacc = fmaf(g.ff, g.ff, nacc);
    }
    return r;
}

__device__ __forceinline__ void pool_half(float* __restrict__ wtile,
                                          const f32x4* __restrict__ a,
                                          const float* __restrict__ riq,
                                          const float* __restrict__ idn,
                                          float (*__restrict__ stot)[12],
                                          int mtbase, int l15, int quad)
{
    #pragma unroll
    for (int nt = 0; nt < 4; ++nt)
        #pragma unroll
        for (int r = 0; r < 4; ++r)
            wtile[(quad * 4 + r) * SSTR + nt * 16 + l15] = a[nt][r] * riq[r] * idn[nt];

    const float* rp = wtile + l15 * SSTR + quad * 16;
    float ksum[KNUM];
    #pragma unroll
    for (int k = 0; k < KNUM; ++k) ksum[k] = 0.f;

    #pragma unroll
    for (int i = 0; i < 4; ++i) {
        const f32x4 sv = *((const f32x4*)(rp + 4 * i));
        #pragma unroll
        for (int e = 0; e < 4; ++e) {
            const float s  = sv[e];
            const float z  = fmaf(s, 10.f, -1.f);
            const float e0 = exp2f(-HALF_L2E * (z * z));
            float ru = exp2f(fmaf(z,  TWO_L2E, -TWO_L2E));
            float rd = exp2f(fmaf(z, -TWO_L2E, -TWO_L2E));
            ksum[5] += e0;
            float tt = e0;
            tt *= ru; ksum[6] += tt; ru *= EM4;
            tt *= ru; ksum[7] += tt; ru *= EM4;
            tt *= ru; ksum[8] += tt; ru *= EM4;
            tt *= ru; ksum[9] += tt;
            tt = e0;
            tt *= rd; ksum[4] += tt; rd *= EM4;
            tt *= rd; ksum[3] += tt; rd *= EM4;
            tt *= rd; ksum[2] += tt; rd *= EM4;
            tt *= rd; ksum[1] += tt; rd *= EM4;
            tt *= rd; ksum[0] += tt;
            ksum[10] += (s > 0.995f) ? 1.f : 0.f;
        }
    }
    #pragma unroll
    for (int k = 0; k < KNUM; ++k) {
        ksum[k] += __shfl_xor(ksum[k], 16);
        ksum[k] += __shfl_xor(ksum[k], 32);
    }
    if (quad == 0) {
        #pragma unroll
        for (int k = 0; k < KNUM; ++k)
            atomicAdd(&stot[mtbase + l15][k], ksum[k]);
    }
}

// Legacy kernel, kept as the small-workspace fallback (instantiated <false>).
template<bool PRE>
__global__ __launch_bounds__(256, 4)
void knrm_pair(const float* __restrict__ emb,
               const ushort* __restrict__ ebf,
               const float* __restrict__ inorm,
               const float* __restrict__ mlp_w,
               const int* __restrict__ q1, const int* __restrict__ d1,
               const int* __restrict__ q2, const int* __restrict__ d2,
               float* __restrict__ logits)
{
    const int b    = blockIdx.x;
    const int pair = blockIdx.y;
    const int t    = threadIdx.x;
    const int w    = t >> 6;
    const int l15  = t & 15;
    const int quad = (t & 63) >> 4;

    const int* __restrict__ qry = (pair == 0 ? q1 : q2) + b * QLEN;
    const int* __restrict__ doc = (pair == 0 ? d1 : d2) + b * DLEN;

    __shared__ __align__(16) float s_sim[4 * SHALF];
    __shared__ float s_tot[QLEN][12];

    #pragma unroll
    for (int i = t; i < QLEN * 12; i += 256) ((float*)s_tot)[i] = 0.f;
    __syncthreads();

    const int qid0 = qry[l15], qid1 = qry[l15 + 16];
    int did[4];
    #pragma unroll
    for (int nt = 0; nt < 4; ++nt) did[nt] = doc[(w * 4 + nt) * 16 + l15];

    f32x4 acc[2][4];
    #pragma unroll
    for (int mt = 0; mt < 2; ++mt)
        #pragma unroll
        for (int nt = 0; nt < 4; ++nt)
            acc[mt][nt] = (f32x4){0.f, 0.f, 0.f, 0.f};

    float idn[4], riq[2][4];
    float* wtile = s_sim + w * SHALF;

    if (PRE) {
        const ushort* qp0 = ebf + (size_t)qid0 * EMBED + quad * 8;
        const ushort* qp1 = ebf + (size_t)qid1 * EMBED + quad * 8;
        #pragma unroll
        for (int kk = 0; kk < 4; ++kk) {
            const bf16x8 a0 = *((const bf16x8*)(qp0 + kk * 32));
            const bf16x8 a1 = *((const bf16x8*)(qp1 + kk * 32));
            #pragma unroll
            for (int nt = 0; nt < 4; ++nt) {
                const bf16x8 bb = *((const bf16x8*)(ebf + (size_t)did[nt] * EMBED + quad * 8 + kk * 32));
                acc[0][nt] = __builtin_amdgcn_mfma_f32_16x16x32_bf16(a0, bb, acc[0][nt], 0, 0, 0);
                acc[1][nt] = __builtin_amdgcn_mfma_f32_16x16x32_bf16(a1, bb, acc[1][nt], 0, 0, 0);
            }
        }
        #pragma unroll
        for (int nt = 0; nt < 4; ++nt) idn[nt] = inorm[did[nt]];
        #pragma unroll
        for (int r = 0; r < 4; ++r) {
            riq[0][r] = inorm[qry[quad * 4 + r]];
            riq[1][r] = inorm[qry[16 + quad * 4 + r]];
        }
    } else {
        float qn2[2] = {0.f, 0.f}, dn2[4] = {0.f, 0.f, 0.f, 0.f};
        const float* qp0 = emb + (size_t)qid0 * EMBED + quad * 8;
        const float* qp1 = emb + (size_t)qid1 * EMBED + quad * 8;
        #pragma unroll
        for (int kk = 0; kk < 4; ++kk) {
            const bf16x8 a0 = cvt8(qp0 + kk * 32, qn2[0]);
            const bf16x8 a1 = cvt8(qp1 + kk * 32, qn2[1]);
            #pragma unroll
            for (int nt = 0; nt < 4; ++nt) {
                const bf16x8 bb = cvt8(emb + (size_t)did[nt] * EMBED + quad * 8 + kk * 32, dn2[nt]);
                acc[0][nt] = __builtin_amdgcn_mfma_f32_16x16x32_bf16(a0, bb, acc[0][nt], 0, 0, 0);
                acc[1][nt] = __builtin_amdgcn_mfma_f32_16x16x32_bf16(a1, bb, acc[1][nt], 0, 0, 0);
            }
        }
        #pragma unroll
        for (int i = 0; i < 2; ++i) {
            qn2[i] += __shfl_xor(qn2[i], 16);
            qn2[i] += __shfl_xor(qn2[i], 32);
        }
        #pragma unroll
        for (int nt = 0; nt < 4; ++nt) {
            dn2[nt] += __shfl_xor(dn2[nt], 16);
            dn2[nt] += __shfl_xor(dn2[nt], 32);
            idn[nt] = __builtin_amdgcn_rsqf(dn2[nt]);
        }
        #pragma unroll
        for (int r = 0; r < 4; ++r) {
            riq[0][r] = __builtin_amdgcn_rsqf(__shfl(qn2[0], quad * 4 + r));
            riq[1][r] = __builtin_amdgcn_rsqf(__shfl(qn2[1], quad * 4 + r));
        }
    }

    pool_half(wtile, acc[0], riq[0], idn, s_tot, 0,  l15, quad);
    pool_half(wtile, acc[1], riq[1], idn, s_tot, 16, l15, quad);
    __syncthreads();

    if (t < QLEN) {
        float c = 0.f;
        #pragma unroll
        for (int k = 0; k < KNUM; ++k) c += mlp_w[k] * log1pf(s_tot[t][k]);
        #pragma unroll
        for (int mm = 1; mm < 32; mm <<= 1) c += __shfl_xor(c, mm);
        if (t == 0) logits[pair * NB + b] = c;
    }
}

__global__ __launch_bounds__(256)
void knrm_combine(const float* __restrict__ logits, float* __restrict__ out)
{
    const int i = blockIdx.x * blockDim.x + threadIdx.x;
    if (i < NB) {
        const float d = logits[i] - logits[NB + i];
        out[i] = 1.f / (1.f + __expf(-d));
    }
}

extern "C" void kernel_launch(void* const* d_in, const int* in_sizes, int n_in,
                              void* d_out, int out_size, void* d_ws, size_t ws_size,
                              hipStream_t stream)
{
    const float* emb   = (const float*)d_in[0];
    const float* mlp_w = (const float*)d_in[1];
    // mlp_b (d_in[2]) unused: cancels in logits1 - logits2
    const int* q1 = (const int*)d_in[3];
    const int* d1 = (const int*)d_in[4];
    const int* q2 = (const int*)d_in[5];
    const int* d2 = (const int*)d_in[6];

    float* out = (float*)d_out;

    const size_t need = 2 * NB * 4                       // logits
                      + (size_t)VOCAB * 4                // inorm
                      + (size_t)VOCAB * EMBED * 2 + 256; // bf16 table
    if (ws_size >= need) {
        float*  logits = (float*)d_ws;
        float*  inorm  = logits + 2 * NB;
        ushort* ebf    = (ushort*)(inorm + VOCAB);
        cvt_table<<<VOCAB / 8, 256, 0, stream>>>(emb, ebf, inorm);
        knrm_pair3<<<dim3(NB, 2), 256, 0, stream>>>(ebf, inorm, mlp_w,
                                                    q1, d1, q2, d2, logits);
    } else {
        float* logits = (float*)d_ws;
        knrm_pair<false><<<dim3(NB, 2), 256, 0, stream>>>(emb, nullptr, nullptr, mlp_w,
                                                          q1, d1, q2, d2, logits);
    }
    knrm_combine<<<(NB + 255) / 256, 256, 0, stream>>>((float*)d_ws, out);
}

// Round 4
// 141.719 us; speedup vs baseline: 1.3216x; 1.1807x over previous
//
#include <hip/hip_runtime.h>
#include <math.h>
#include <stdint.h>

#define VOCAB 100000
#define NB    1024
#define QLEN  32
#define DLEN  256
#define EMBED 128
#define KNUM  11

typedef __attribute__((ext_vector_type(8))) short bf16x8;   // 8 bf16 = 4 VGPRs
typedef __attribute__((ext_vector_type(4))) float f32x4;

// Gaussian chain: mus -0.9..0.9 step 0.2 (sigma 0.1) + exact mu=1 sigma=.001
#define HALF_L2E 0.7213475204444817f   // 0.5*log2(e)
#define TWO_L2E  2.8853900817779268f   // 2*log2(e)
#define EM4      0.018315638888734179f // e^-4

// Wave-private sim half-tile: [m=16][n=64], row stride 68 (16B-aligned rows,
// 2-way bank aliasing = free per m136).
#define SSTR  68
#define SHALF (16 * SSTR)

// ---------- prepass: fp32 table -> bf16 table + bf16-consistent inv-norms ----
__global__ __launch_bounds__(256)
void cvt_table(const float* __restrict__ emb, ushort* __restrict__ ebf,
               float* __restrict__ inorm)
{
    const int row = blockIdx.x * 8 + (threadIdx.x >> 5);
    const int l32 = threadIdx.x & 31;
    const float4 v = *((const float4*)(emb + (size_t)row * EMBED) + l32);
    union { float f; unsigned u; } x0, x1, x2, x3;
    x0.f = v.x; x1.f = v.y; x2.f = v.z; x3.f = v.w;
    const unsigned r0 = x0.u + 0x8000u, r1 = x1.u + 0x8000u;  // round-half-up
    const unsigned r2 = x2.u + 0x8000u, r3 = x3.u + 0x8000u;
    uint2 packed;
    packed.x = (r0 >> 16) | (r1 & 0xFFFF0000u);
    packed.y = (r2 >> 16) | (r3 & 0xFFFF0000u);
    *((uint2*)(ebf + (size_t)row * EMBED) + l32) = packed;
    x0.u = r0 & 0xFFFF0000u; x1.u = r1 & 0xFFFF0000u;
    x2.u = r2 & 0xFFFF0000u; x3.u = r3 & 0xFFFF0000u;
    float n = x0.f * x0.f + x1.f * x1.f + x2.f * x2.f + x3.f * x3.f;
    #pragma unroll
    for (int m = 1; m < 32; m <<= 1) n += __shfl_xor(n, m);
    if (l32 == 0) inorm[row] = __builtin_amdgcn_rsqf(n);
}

// ---------------------------------------------------------------------------
// fallback helper: fp32 -> bf16 frag + norm of rounded values
__device__ __forceinline__ bf16x8 cvt8(const float* p, float& nacc)
{
    uint4 a = *((const uint4*)p);
    uint4 b = *((const uint4*)(p + 4));
    unsigned u[8] = {a.x, a.y, a.z, a.w, b.x, b.y, b.z, b.w};
    bf16x8 r;
    #pragma unroll
    for (int i = 0; i < 8; ++i) {
        const unsigned q = u[i] + 0x8000u;
        r[i] = (short)(q >> 16);
        union { unsigned uu; float ff; } g; g.uu = q & 0xFFFF0000u;
        nacc = fmaf(g.ff, g.ff, nacc);
    }
    return r;
}

// pool one 16-row half-tile: write sims, exp-chain, reduce, atomic into s_tot
__device__ __forceinline__ void pool_half(float* __restrict__ wtile,
                                          const f32x4* __restrict__ a,   // [4] nt
                                          const float* __restrict__ riq, // [4] r
                                          const float* __restrict__ idn, // [4] nt
                                          float (*__restrict__ stot)[12],
                                          int mtbase, int l15, int quad)
{
    #pragma unroll
    for (int nt = 0; nt < 4; ++nt)
        #pragma unroll
        for (int r = 0; r < 4; ++r)
            wtile[(quad * 4 + r) * SSTR + nt * 16 + l15] = a[nt][r] * riq[r] * idn[nt];

    const float* rp = wtile + l15 * SSTR + quad * 16;   // row l15, chunk quad
    float ksum[KNUM];
    #pragma unroll
    for (int k = 0; k < KNUM; ++k) ksum[k] = 0.f;

    #pragma unroll
    for (int i = 0; i < 4; ++i) {
        const f32x4 sv = *((const f32x4*)(rp + 4 * i));
        #pragma unroll
        for (int e = 0; e < 4; ++e) {
            const float s  = sv[e];
            const float z  = fmaf(s, 10.f, -1.f);
            const float e0 = exp2f(-HALF_L2E * (z * z));
            float ru = exp2f(fmaf(z,  TWO_L2E, -TWO_L2E));
            float rd = exp2f(fmaf(z, -TWO_L2E, -TWO_L2E));
            ksum[5] += e0;
            float tt = e0;
            tt *= ru; ksum[6] += tt; ru *= EM4;
            tt *= ru; ksum[7] += tt; ru *= EM4;
            tt *= ru; ksum[8] += tt; ru *= EM4;
            tt *= ru; ksum[9] += tt;
            tt = e0;
            tt *= rd; ksum[4] += tt; rd *= EM4;
            tt *= rd; ksum[3] += tt; rd *= EM4;
            tt *= rd; ksum[2] += tt; rd *= EM4;
            tt *= rd; ksum[1] += tt; rd *= EM4;
            tt *= rd; ksum[0] += tt;
            // exact kernel (sigma=.001): ==1 iff token match (bf16 self-sim
            // 1+-3e-6; non-match needs cos>0.995 ~ 11 sigma)
            ksum[10] += (s > 0.995f) ? 1.f : 0.f;
        }
    }
    #pragma unroll
    for (int k = 0; k < KNUM; ++k) {
        ksum[k] += __shfl_xor(ksum[k], 16);
        ksum[k] += __shfl_xor(ksum[k], 32);
    }
    if (quad == 0) {
        #pragma unroll
        for (int k = 0; k < KNUM; ++k)
            atomicAdd(&stot[mtbase + l15][k], ksum[k]);
    }
}

// ---------------------------------------------------------------------------
// Round-4: EXACT legacy structure (4 waves, wave-private s_sim pooling, 53us
// proven) + compiler-proof full load hoist. All 24 frag gathers issue
// back-to-back, pinned by asm volatile consumers (data dep -> loads stay
// above) + sched_barrier(0) (MFMAs stay below). One vmcnt wait point per
// wave with 24 loads outstanding, vs ~4-6 in the legacy schedule.
// GATE: VGPR_Count must be ~130-165 (52 = hoist defeated again);
//       WRITE_SIZE must stay ~64 KB (MBs = spill).
__global__ __launch_bounds__(256, 3)
void knrm_pair4(const ushort* __restrict__ ebf,
                const float* __restrict__ inorm,
                const float* __restrict__ mlp_w,
                const int* __restrict__ q1, const int* __restrict__ d1,
                const int* __restrict__ q2, const int* __restrict__ d2,
                float* __restrict__ logits)
{
    const int b    = blockIdx.x;
    const int pair = blockIdx.y;
    const int t    = threadIdx.x;
    const int w    = t >> 6;        // wave id: doc tiles w*4..w*4+3
    const int l15  = t & 15;
    const int quad = (t & 63) >> 4;

    const int* __restrict__ qry = (pair == 0 ? q1 : q2) + b * QLEN;
    const int* __restrict__ doc = (pair == 0 ? d1 : d2) + b * DLEN;

    __shared__ __align__(16) float s_sim[4 * SHALF];   // 17408 B wave-private
    __shared__ float s_tot[QLEN][12];                  // 1536 B

    // ---- ids (independent, oldest vmem) ----
    const int qid0 = qry[l15], qid1 = qry[l15 + 16];
    int did[4];
    #pragma unroll
    for (int j = 0; j < 4; ++j) did[j] = doc[(w * 4 + j) * 16 + l15];

    // ---- all 24 fragment gathers, issued before any compute ----
    bf16x8 a0[4], a1[4], bbf[4][4];
    {
        const ushort* qp0 = ebf + (size_t)qid0 * EMBED + quad * 8;
        const ushort* qp1 = ebf + (size_t)qid1 * EMBED + quad * 8;
        #pragma unroll
        for (int kk = 0; kk < 4; ++kk) {
            a0[kk] = *(const bf16x8*)(qp0 + kk * 32);
            a1[kk] = *(const bf16x8*)(qp1 + kk * 32);
        }
        #pragma unroll
        for (int j = 0; j < 4; ++j) {
            const ushort* dp = ebf + (size_t)did[j] * EMBED + quad * 8;
            #pragma unroll
            for (int kk = 0; kk < 4; ++kk)
                bbf[j][kk] = *(const bf16x8*)(dp + kk * 32);
        }
    }
    // norm gathers: consumed only in pooling -> stay in flight through MFMA
    float idn[4];
    #pragma unroll
    for (int j = 0; j < 4; ++j) idn[j] = inorm[did[j]];
    float riq[2][4];
    #pragma unroll
    for (int r = 0; r < 4; ++r) {
        riq[0][r] = inorm[qry[quad * 4 + r]];
        riq[1][r] = inorm[qry[16 + quad * 4 + r]];
    }

    // zero s_tot while the gathers fly
    #pragma unroll
    for (int i = t; i < QLEN * 12; i += 256) ((float*)s_tot)[i] = 0.f;

    // ---- pin: loads can't sink below (data dep), MFMAs can't hoist above ----
    #pragma unroll
    for (int kk = 0; kk < 4; ++kk)
        asm volatile("" :: "v"(a0[kk]), "v"(a1[kk]));
    #pragma unroll
    for (int j = 0; j < 4; ++j)
        asm volatile("" :: "v"(bbf[j][0]), "v"(bbf[j][1]),
                          "v"(bbf[j][2]), "v"(bbf[j][3]));
    __builtin_amdgcn_sched_barrier(0);

    // ---- MFMA: 32 q-rows x 64 doc-cols x K=128 per wave ----
    f32x4 acc[2][4];
    #pragma unroll
    for (int mt = 0; mt < 2; ++mt)
        #pragma unroll
        for (int j = 0; j < 4; ++j)
            acc[mt][j] = (f32x4){0.f, 0.f, 0.f, 0.f};
    #pragma unroll
    for (int kk = 0; kk < 4; ++kk)
        #pragma unroll
        for (int j = 0; j < 4; ++j) {
            acc[0][j] = __builtin_amdgcn_mfma_f32_16x16x32_bf16(a0[kk], bbf[j][kk], acc[0][j], 0, 0, 0);
            acc[1][j] = __builtin_amdgcn_mfma_f32_16x16x32_bf16(a1[kk], bbf[j][kk], acc[1][j], 0, 0, 0);
        }

    __syncthreads();        // s_tot zeros visible before pooling atomics

    float* wtile = s_sim + w * SHALF;
    pool_half(wtile, acc[0], riq[0], idn, s_tot, 0,  l15, quad);
    pool_half(wtile, acc[1], riq[1], idn, s_tot, 16, l15, quad);
    __syncthreads();

    if (t < QLEN) {
        float c = 0.f;
        #pragma unroll
        for (int k = 0; k < KNUM; ++k) c += mlp_w[k] * log1pf(s_tot[t][k]);
        #pragma unroll
        for (int mm = 1; mm < 32; mm <<= 1) c += __shfl_xor(c, mm);
        if (t == 0) logits[pair * NB + b] = c;   // mlp bias cancels in l1-l2
    }
}

// Legacy kernel, kept as the small-workspace fallback (instantiated <false>).
template<bool PRE>
__global__ __launch_bounds__(256, 4)
void knrm_pair(const float* __restrict__ emb,
               const ushort* __restrict__ ebf,
               const float* __restrict__ inorm,
               const float* __restrict__ mlp_w,
               const int* __restrict__ q1, const int* __restrict__ d1,
               const int* __restrict__ q2, const int* __restrict__ d2,
               float* __restrict__ logits)
{
    const int b    = blockIdx.x;
    const int pair = blockIdx.y;
    const int t    = threadIdx.x;
    const int w    = t >> 6;
    const int l15  = t & 15;
    const int quad = (t & 63) >> 4;

    const int* __restrict__ qry = (pair == 0 ? q1 : q2) + b * QLEN;
    const int* __restrict__ doc = (pair == 0 ? d1 : d2) + b * DLEN;

    __shared__ __align__(16) float s_sim[4 * SHALF];
    __shared__ float s_tot[QLEN][12];

    #pragma unroll
    for (int i = t; i < QLEN * 12; i += 256) ((float*)s_tot)[i] = 0.f;
    __syncthreads();

    const int qid0 = qry[l15], qid1 = qry[l15 + 16];
    int did[4];
    #pragma unroll
    for (int nt = 0; nt < 4; ++nt) did[nt] = doc[(w * 4 + nt) * 16 + l15];

    f32x4 acc[2][4];
    #pragma unroll
    for (int mt = 0; mt < 2; ++mt)
        #pragma unroll
        for (int nt = 0; nt < 4; ++nt)
            acc[mt][nt] = (f32x4){0.f, 0.f, 0.f, 0.f};

    float idn[4], riq[2][4];
    float* wtile = s_sim + w * SHALF;

    if (PRE) {
        const ushort* qp0 = ebf + (size_t)qid0 * EMBED + quad * 8;
        const ushort* qp1 = ebf + (size_t)qid1 * EMBED + quad * 8;
        #pragma unroll
        for (int kk = 0; kk < 4; ++kk) {
            const bf16x8 a0 = *((const bf16x8*)(qp0 + kk * 32));
            const bf16x8 a1 = *((const bf16x8*)(qp1 + kk * 32));
            #pragma unroll
            for (int nt = 0; nt < 4; ++nt) {
                const bf16x8 bb = *((const bf16x8*)(ebf + (size_t)did[nt] * EMBED + quad * 8 + kk * 32));
                acc[0][nt] = __builtin_amdgcn_mfma_f32_16x16x32_bf16(a0, bb, acc[0][nt], 0, 0, 0);
                acc[1][nt] = __builtin_amdgcn_mfma_f32_16x16x32_bf16(a1, bb, acc[1][nt], 0, 0, 0);
            }
        }
        #pragma unroll
        for (int nt = 0; nt < 4; ++nt) idn[nt] = inorm[did[nt]];
        #pragma unroll
        for (int r = 0; r < 4; ++r) {
            riq[0][r] = inorm[qry[quad * 4 + r]];
            riq[1][r] = inorm[qry[16 + quad * 4 + r]];
        }
    } else {
        float qn2[2] = {0.f, 0.f}, dn2[4] = {0.f, 0.f, 0.f, 0.f};
        const float* qp0 = emb + (size_t)qid0 * EMBED + quad * 8;
        const float* qp1 = emb + (size_t)qid1 * EMBED + quad * 8;
        #pragma unroll
        for (int kk = 0; kk < 4; ++kk) {
            const bf16x8 a0 = cvt8(qp0 + kk * 32, qn2[0]);
            const bf16x8 a1 = cvt8(qp1 + kk * 32, qn2[1]);
            #pragma unroll
            for (int nt = 0; nt < 4; ++nt) {
                const bf16x8 bb = cvt8(emb + (size_t)did[nt] * EMBED + quad * 8 + kk * 32, dn2[nt]);
                acc[0][nt] = __builtin_amdgcn_mfma_f32_16x16x32_bf16(a0, bb, acc[0][nt], 0, 0, 0);
                acc[1][nt] = __builtin_amdgcn_mfma_f32_16x16x32_bf16(a1, bb, acc[1][nt], 0, 0, 0);
            }
        }
        #pragma unroll
        for (int i = 0; i < 2; ++i) {
            qn2[i] += __shfl_xor(qn2[i], 16);
            qn2[i] += __shfl_xor(qn2[i], 32);
        }
        #pragma unroll
        for (int nt = 0; nt < 4; ++nt) {
            dn2[nt] += __shfl_xor(dn2[nt], 16);
            dn2[nt] += __shfl_xor(dn2[nt], 32);
            idn[nt] = __builtin_amdgcn_rsqf(dn2[nt]);
        }
        #pragma unroll
        for (int r = 0; r < 4; ++r) {
            riq[0][r] = __builtin_amdgcn_rsqf(__shfl(qn2[0], quad * 4 + r));
            riq[1][r] = __builtin_amdgcn_rsqf(__shfl(qn2[1], quad * 4 + r));
        }
    }

    pool_half(wtile, acc[0], riq[0], idn, s_tot, 0,  l15, quad);
    pool_half(wtile, acc[1], riq[1], idn, s_tot, 16, l15, quad);
    __syncthreads();

    if (t < QLEN) {
        float c = 0.f;
        #pragma unroll
        for (int k = 0; k < KNUM; ++k) c += mlp_w[k] * log1pf(s_tot[t][k]);
        #pragma unroll
        for (int mm = 1; mm < 32; mm <<= 1) c += __shfl_xor(c, mm);
        if (t == 0) logits[pair * NB + b] = c;
    }
}

__global__ __launch_bounds__(256)
void knrm_combine(const float* __restrict__ logits, float* __restrict__ out)
{
    const int i = blockIdx.x * blockDim.x + threadIdx.x;
    if (i < NB) {
        const float d = logits[i] - logits[NB + i];
        out[i] = 1.f / (1.f + __expf(-d));
    }
}

extern "C" void kernel_launch(void* const* d_in, const int* in_sizes, int n_in,
                              void* d_out, int out_size, void* d_ws, size_t ws_size,
                              hipStream_t stream)
{
    const float* emb   = (const float*)d_in[0];
    const float* mlp_w = (const float*)d_in[1];
    // mlp_b (d_in[2]) unused: cancels in logits1 - logits2
    const int* q1 = (const int*)d_in[3];
    const int* d1 = (const int*)d_in[4];
    const int* q2 = (const int*)d_in[5];
    const int* d2 = (const int*)d_in[6];

    float* out = (float*)d_out;

    const size_t need = 2 * NB * 4                       // logits
                      + (size_t)VOCAB * 4                // inorm
                      + (size_t)VOCAB * EMBED * 2 + 256; // bf16 table
    if (ws_size >= need) {
        float*  logits = (float*)d_ws;
        float*  inorm  = logits + 2 * NB;
        ushort* ebf    = (ushort*)(inorm + VOCAB);
        cvt_table<<<VOCAB / 8, 256, 0, stream>>>(emb, ebf, inorm);
        knrm_pair4<<<dim3(NB, 2), 256, 0, stream>>>(ebf, inorm, mlp_w,
                                                    q1, d1, q2, d2, logits);
    } else {
        float* logits = (float*)d_ws;
        knrm_pair<false><<<dim3(NB, 2), 256, 0, stream>>>(emb, nullptr, nullptr, mlp_w,
                                                          q1, d1, q2, d2, logits);
    }
    knrm_combine<<<(NB + 255) / 256, 256, 0, stream>>>((float*)d_ws, out);
}